// Round 5
// baseline (96.414 us; speedup 1.0000x reference)
//
#include <hip/hip_runtime.h>
#include <math.h>

#define W 128

typedef float f2_t __attribute__((ext_vector_type(2)));

__device__ __forceinline__ int refl128(int i) {
    i = (i < 0) ? (-1 - i) : i;        // symmetric (half-sample) reflect
    return (i > 127) ? (255 - i) : i;
}

__device__ __forceinline__ float magf(float re, float im) {
    return sqrtf(fmaf(re, re, fmaf(im, im, 1.0e-4f))) - 0.01f;
}

__device__ __forceinline__ void st2(float* p, float a, float b) {
    f2_t v;
    v.x = a; v.y = b;
    __builtin_nontemporal_store(v, (f2_t*)p);
}

// 7-tap symmetric vertical dot over float4 rows A..G
__device__ __forceinline__ float4 d7(float4 A, float4 B, float4 C, float4 D,
                                     float4 E, float4 F, float4 G,
                                     float k0, float k1, float k2, float k3) {
    float4 r;
    r.x = fmaf(k0, A.x + G.x, fmaf(k1, B.x + F.x, fmaf(k2, C.x + E.x, k3 * D.x)));
    r.y = fmaf(k0, A.y + G.y, fmaf(k1, B.y + F.y, fmaf(k2, C.y + E.y, k3 * D.y)));
    r.z = fmaf(k0, A.z + G.z, fmaf(k1, B.z + F.z, fmaf(k2, C.z + E.z, k3 * D.z)));
    r.w = fmaf(k0, A.w + G.w, fmaf(k1, B.w + F.w, fmaf(k2, C.w + E.w, k3 * D.w)));
    return r;
}

// 5-tap symmetric vertical dot over float4 rows A..E
__device__ __forceinline__ float4 d5(float4 A, float4 B, float4 C, float4 D, float4 E,
                                     float k0, float k1, float k2) {
    float4 r;
    r.x = fmaf(k0, A.x + E.x, fmaf(k1, B.x + D.x, k2 * C.x));
    r.y = fmaf(k0, A.y + E.y, fmaf(k1, B.y + D.y, k2 * C.y));
    r.z = fmaf(k0, A.z + E.z, fmaf(k1, B.z + D.z, k2 * C.z));
    r.w = fmaf(k0, A.w + E.w, fmaf(k1, B.w + D.w, k2 * C.w));
    return r;
}

struct Row { float4 lo, hi; };

// horizontal 5/7-tap filters for this thread's 4 columns of full-res row q
__device__ __forceinline__ Row hfilt(const float4* __restrict__ rv, int g) {
    const float4 B = rv[g];
    float4 A = rv[g > 0 ? g - 1 : 0];
    float4 C = rv[g < 31 ? g + 1 : 31];
    const float4 revB = make_float4(B.w, B.z, B.y, B.x);
    if (g == 0)  A = revB;             // cols -4..-1 reflected
    if (g == 31) C = revB;             // cols 128..131 reflected
    const float wv[10] = {A.y, A.z, A.w, B.x, B.y, B.z, B.w, C.x, C.y, C.z};
    Row r;
    float* lop  = &r.lo.x;
    float* hip_ = &r.hi.x;
    #pragma unroll
    for (int j = 0; j < 4; ++j) {
        const float sA = wv[j]     + wv[j + 6];
        const float sB = wv[j + 1] + wv[j + 5];
        const float sC = wv[j + 2] + wv[j + 4];
        const float ct = wv[j + 3];
        lop[j]  = fmaf(-0.05f, sB, fmaf(0.25f, sC, 0.5f * ct));
        hip_[j] = fmaf(-0.0107143f, sA,
                  fmaf( 0.0535714f, sB,
                  fmaf( 0.2607143f, sC, -0.6071429f * ct)));
    }
    return r;
}

// emit one output half-row (2 output cols) from the 8-row window
__device__ __forceinline__ void emit(const float4 (&L)[8], const float4 (&H)[8],
                                     float* __restrict__ llp,
                                     float* __restrict__ rp) {
    const float S  = 0.70710678118654752f;
    const float a7 = -0.0107143f * S, b7 = 0.0535714f * S,
                c7 =  0.2607143f * S, d7c = -0.6071429f * S;
    const float a5 = -0.05f * S, b5 = 0.25f * S, c5 = 0.5f * S;

    // lh -> 15 / 165   (keep L-derived and H-derived separate to cap live VGPRs)
    {
        const float4 t  = d7(L[0], L[1], L[2], L[3], L[4], L[5], L[6], a7, b7, c7, d7c);
        const float4 bo = d7(L[1], L[2], L[3], L[4], L[5], L[6], L[7], a7, b7, c7, d7c);
        st2(rp + 0u * 262144u, magf(t.x - bo.y, t.y + bo.x), magf(t.z - bo.w, t.w + bo.z));
        st2(rp + 5u * 262144u, magf(t.x + bo.y, t.y - bo.x), magf(t.z + bo.w, t.w - bo.z));
    }
    // ll -> 2x2 pool (0.25 folded into taps)
    {
        const float4 t  = d5(L[1], L[2], L[3], L[4], L[5], -0.0125f, 0.0625f, 0.125f);
        const float4 bo = d5(L[2], L[3], L[4], L[5], L[6], -0.0125f, 0.0625f, 0.125f);
        st2(llp, (t.x + t.y) + (bo.x + bo.y), (t.z + t.w) + (bo.z + bo.w));
    }
    // hh -> 45 / 135
    {
        const float4 t  = d7(H[0], H[1], H[2], H[3], H[4], H[5], H[6], a7, b7, c7, d7c);
        const float4 bo = d7(H[1], H[2], H[3], H[4], H[5], H[6], H[7], a7, b7, c7, d7c);
        st2(rp + 1u * 262144u, magf(t.x - bo.y, t.y + bo.x), magf(t.z - bo.w, t.w + bo.z));
        st2(rp + 4u * 262144u, magf(t.x + bo.y, t.y - bo.x), magf(t.z + bo.w, t.w - bo.z));
    }
    // hl -> 75 / 105
    {
        const float4 t  = d5(H[1], H[2], H[3], H[4], H[5], a5, b5, c5);
        const float4 bo = d5(H[2], H[3], H[4], H[5], H[6], a5, b5, c5);
        st2(rp + 2u * 262144u, magf(t.x - bo.y, t.y + bo.x), magf(t.z - bo.w, t.w + bo.z));
        st2(rp + 3u * 262144u, magf(t.x + bo.y, t.y - bo.x), magf(t.z + bo.w, t.w - bo.z));
    }
}

__global__ __launch_bounds__(256) void scat_j1_kernel(
    const float* __restrict__ x,
    float* __restrict__ out_ll,
    float* __restrict__ out_r)
{
    const int tid   = threadIdx.x;
    const int g     = tid & 31;        // 4-col group 0..31
    const int strip = tid >> 5;        // 0..7, 16 full-res rows each
    const int plane = blockIdx.x;      // 0..2047
    const int n     = plane >> 6;
    const int ch    = plane & 63;
    const int r0    = strip * 16;

    const float* __restrict__ xp = x + (size_t)plane * (W * W);

    float4 L[8], H[8];

    // fill window: full-res rows r0-3 .. r0+4
    #pragma unroll
    for (int p = 0; p < 4; ++p) {
        #pragma unroll
        for (int s = 0; s < 2; ++s) {
            const int q = refl128(r0 - 3 + 2 * p + s);
            const Row rr = hfilt((const float4*)(xp + (size_t)q * W), g);
            L[2 * p + s] = rr.lo;
            H[2 * p + s] = rr.hi;
        }
    }

    float* llp = out_ll + (size_t)plane * 4096 + (size_t)(strip * 8) * 64 + 2 * g;
    float* rp  = out_r + ((size_t)(n * 384 + ch)) * 4096 + (size_t)(strip * 8) * 64 + 2 * g;

    emit(L, H, llp, rp);               // h = 0

    #pragma unroll
    for (int p = 4; p <= 10; ++p) {    // h = p-3 = 1..7
        #pragma unroll
        for (int t = 0; t < 6; ++t) { L[t] = L[t + 2]; H[t] = H[t + 2]; }
        #pragma unroll
        for (int s = 0; s < 2; ++s) {
            const int q = refl128(r0 - 3 + 2 * p + s);
            const Row rr = hfilt((const float4*)(xp + (size_t)q * W), g);
            L[6 + s] = rr.lo;
            H[6 + s] = rr.hi;
        }
        llp += 64;
        rp  += 64;
        emit(L, H, llp, rp);
    }
}

extern "C" void kernel_launch(void* const* d_in, const int* in_sizes, int n_in,
                              void* d_out, int out_size, void* d_ws, size_t ws_size,
                              hipStream_t stream) {
    const float* x = (const float*)d_in[0];
    float* out = (float*)d_out;
    float* out_ll = out;                 // 32*64*64*64 = 8388608 floats
    float* out_r  = out + 8388608;       // 32*384*64*64 = 50331648 floats

    dim3 grid(2048);                     // one block per (n,c) plane
    dim3 block(256);                     // 8 strips x 32 col-groups
    hipLaunchKernelGGL(scat_j1_kernel, grid, block, 0, stream, x, out_ll, out_r);
}

// Round 6
// 89.018 us; speedup vs baseline: 1.0831x; 1.0831x over previous
//
#include <hip/hip_runtime.h>
#include <math.h>

#define W 128
#define LROWS 22                   // 16 rows + 6 halo
#define TILE_IN 16
#define TILE_OUT 8
#define TPB 4                      // tiles per block (half a plane)

typedef float f2_t __attribute__((ext_vector_type(2)));

__device__ __forceinline__ int refl128(int i) {
    i = (i < 0) ? (-1 - i) : i;    // symmetric (half-sample) reflect
    return (i > 127) ? (255 - i) : i;
}

__device__ __forceinline__ float magf(float re, float im) {
    return sqrtf(fmaf(re, re, fmaf(im, im, 1.0e-4f))) - 0.01f;
}

__device__ __forceinline__ void st2(float* p, float a, float b) {
    f2_t v; v.x = a; v.y = b;
    __builtin_nontemporal_store(v, (f2_t*)p);
}

struct Pf { float4 a, b, c; };

// issue the 9 global loads for one tile into registers (no compute)
__device__ __forceinline__ void pf_tile(const float* __restrict__ xp, int r0,
                                        int g, int rb, Pf pf[3]) {
    #pragma unroll
    for (int it = 0; it < 3; ++it) {
        const int lr = it * 8 + rb;
        if (lr < LROWS) {
            const int q = refl128(r0 - 3 + lr);
            const float4* __restrict__ rv = (const float4*)(xp + (size_t)q * W);
            pf[it].b = rv[g];
            pf[it].a = rv[g > 0 ? g - 1 : 0];
            pf[it].c = rv[g < 31 ? g + 1 : 31];
        }
    }
}

// horizontal 5/7-tap filters from prefetched regs -> LDS
__device__ __forceinline__ void hwrite(const Pf pf[3], int g, int rb,
                                       float (* __restrict__ slo)[W],
                                       float (* __restrict__ shi)[W]) {
    #pragma unroll
    for (int it = 0; it < 3; ++it) {
        const int lr = it * 8 + rb;
        if (lr < LROWS) {
            float4 A = pf[it].a;
            const float4 B = pf[it].b;
            float4 C = pf[it].c;
            const float4 revB = make_float4(B.w, B.z, B.y, B.x);
            if (g == 0)  A = revB;          // cols -4..-1 reflected
            if (g == 31) C = revB;          // cols 128..131 reflected
            const float wv[10] = {A.y, A.z, A.w, B.x, B.y, B.z, B.w, C.x, C.y, C.z};
            float4 lo4, hi4;
            float* lop = &lo4.x;
            float* hp  = &hi4.x;
            #pragma unroll
            for (int j = 0; j < 4; ++j) {
                const float sA = wv[j]     + wv[j + 6];
                const float sB = wv[j + 1] + wv[j + 5];
                const float sC = wv[j + 2] + wv[j + 4];
                const float ct = wv[j + 3];
                lop[j] = fmaf(-0.05f, sB, fmaf(0.25f, sC, 0.5f * ct));
                hp[j]  = fmaf(-0.0107143f, sA,
                         fmaf( 0.0535714f, sB,
                         fmaf( 0.2607143f, sC, -0.6071429f * ct)));
            }
            ((float4*)&slo[lr][0])[g] = lo4;
            ((float4*)&shi[lr][0])[g] = hi4;
        }
    }
}

// vertical filters + q2c + magnitudes + ll pool for one tile (identical to R3)
__device__ __forceinline__ void phase2(const float (* __restrict__ slo)[W],
                                       const float (* __restrict__ shi)[W],
                                       int tid, int tile_abs, int plane,
                                       float* __restrict__ out_ll,
                                       float* __restrict__ out_r) {
    const int J     = tid & 63;        // output col 0..63
    const int Ib    = tid >> 6;        // 0..3 -> owns half-rows Ib*2, Ib*2+1
    const int c0    = 2 * J;
    const int n     = plane >> 6;
    const int ch    = plane & 63;
    const int Rbase = Ib * 4;
    const float S   = 0.70710678118654752f;

    float2 L[8], H[8];
    #pragma unroll
    for (int t = 0; t < 8; ++t) {
        L[t] = *(const float2*)&slo[Rbase + t][c0];
        H[t] = *(const float2*)&shi[Rbase + t][c0];
    }

    #pragma unroll
    for (int k = 0; k < 2; ++k) {
        float2 lh_t, lh_b, ll_t, ll_b, hh_t, hh_b, hl_t, hl_b;
        {
            lh_t.x = fmaf(-0.0107143f, L[0].x + L[6].x, fmaf(0.0535714f, L[1].x + L[5].x, fmaf(0.2607143f, L[2].x + L[4].x, -0.6071429f * L[3].x)));
            lh_t.y = fmaf(-0.0107143f, L[0].y + L[6].y, fmaf(0.0535714f, L[1].y + L[5].y, fmaf(0.2607143f, L[2].y + L[4].y, -0.6071429f * L[3].y)));
            lh_b.x = fmaf(-0.0107143f, L[1].x + L[7].x, fmaf(0.0535714f, L[2].x + L[6].x, fmaf(0.2607143f, L[3].x + L[5].x, -0.6071429f * L[4].x)));
            lh_b.y = fmaf(-0.0107143f, L[1].y + L[7].y, fmaf(0.0535714f, L[2].y + L[6].y, fmaf(0.2607143f, L[3].y + L[5].y, -0.6071429f * L[4].y)));
            ll_t.x = fmaf(-0.05f, L[1].x + L[5].x, fmaf(0.25f, L[2].x + L[4].x, 0.5f * L[3].x));
            ll_t.y = fmaf(-0.05f, L[1].y + L[5].y, fmaf(0.25f, L[2].y + L[4].y, 0.5f * L[3].y));
            ll_b.x = fmaf(-0.05f, L[2].x + L[6].x, fmaf(0.25f, L[3].x + L[5].x, 0.5f * L[4].x));
            ll_b.y = fmaf(-0.05f, L[2].y + L[6].y, fmaf(0.25f, L[3].y + L[5].y, 0.5f * L[4].y));
            hh_t.x = fmaf(-0.0107143f, H[0].x + H[6].x, fmaf(0.0535714f, H[1].x + H[5].x, fmaf(0.2607143f, H[2].x + H[4].x, -0.6071429f * H[3].x)));
            hh_t.y = fmaf(-0.0107143f, H[0].y + H[6].y, fmaf(0.0535714f, H[1].y + H[5].y, fmaf(0.2607143f, H[2].y + H[4].y, -0.6071429f * H[3].y)));
            hh_b.x = fmaf(-0.0107143f, H[1].x + H[7].x, fmaf(0.0535714f, H[2].x + H[6].x, fmaf(0.2607143f, H[3].x + H[5].x, -0.6071429f * H[4].x)));
            hh_b.y = fmaf(-0.0107143f, H[1].y + H[7].y, fmaf(0.0535714f, H[2].y + H[6].y, fmaf(0.2607143f, H[3].y + H[5].y, -0.6071429f * H[4].y)));
            hl_t.x = fmaf(-0.05f, H[1].x + H[5].x, fmaf(0.25f, H[2].x + H[4].x, 0.5f * H[3].x));
            hl_t.y = fmaf(-0.05f, H[1].y + H[5].y, fmaf(0.25f, H[2].y + H[4].y, 0.5f * H[3].y));
            hl_b.x = fmaf(-0.05f, H[2].x + H[6].x, fmaf(0.25f, H[3].x + H[5].x, 0.5f * H[4].x));
            hl_b.y = fmaf(-0.05f, H[2].y + H[6].y, fmaf(0.25f, H[3].y + H[5].y, 0.5f * H[4].y));
        }

        float a, b, c_, d;
        a = S * lh_t.x; b = S * lh_t.y; c_ = S * lh_b.x; d = S * lh_b.y;
        const float m15  = magf(a - d, b + c_);
        const float m165 = magf(a + d, b - c_);
        a = S * hh_t.x; b = S * hh_t.y; c_ = S * hh_b.x; d = S * hh_b.y;
        const float m45  = magf(a - d, b + c_);
        const float m135 = magf(a + d, b - c_);
        a = S * hl_t.x; b = S * hl_t.y; c_ = S * hl_b.x; d = S * hl_b.y;
        const float m75  = magf(a - d, b + c_);
        const float m105 = magf(a + d, b - c_);

        const int Il = Ib * 2 + k;
        const int I  = tile_abs * TILE_OUT + Il;

        __builtin_nontemporal_store(
            0.25f * (ll_t.x + ll_t.y + ll_b.x + ll_b.y),
            &out_ll[(size_t)plane * 4096 + I * 64 + J]);

        float* rp = out_r + ((size_t)(n * 384 + ch)) * 4096 + (size_t)I * 64 + J;
        __builtin_nontemporal_store(m15,  rp + 0u * 262144);
        __builtin_nontemporal_store(m45,  rp + 1u * 262144);
        __builtin_nontemporal_store(m75,  rp + 2u * 262144);
        __builtin_nontemporal_store(m105, rp + 3u * 262144);
        __builtin_nontemporal_store(m135, rp + 4u * 262144);
        __builtin_nontemporal_store(m165, rp + 5u * 262144);

        if (k == 0) {
            #pragma unroll
            for (int t = 0; t < 6; ++t) { L[t] = L[t + 2]; H[t] = H[t + 2]; }
            const int rn = Rbase + 8;
            L[6] = *(const float2*)&slo[rn][c0];
            L[7] = *(const float2*)&slo[rn + 1][c0];
            H[6] = *(const float2*)&shi[rn][c0];
            H[7] = *(const float2*)&shi[rn + 1][c0];
        }
    }
}

__global__ __launch_bounds__(256) void scat_j1_kernel(
    const float* __restrict__ x,
    float* __restrict__ out_ll,
    float* __restrict__ out_r)
{
    __shared__ float slo[2][LROWS][W];
    __shared__ float shi[2][LROWS][W];

    // XCD-chunked swizzle (grid 4096 = 8 * 512): same-plane halves adjacent on one XCD
    const int raw   = blockIdx.x;
    const int L_id  = (raw & 7) * 512 + (raw >> 3);
    const int plane = L_id >> 1;       // 0..2047
    const int half  = L_id & 1;        // 0..1 -> tiles 0-3 / 4-7
    const int tid   = threadIdx.x;
    const int g     = tid & 31;
    const int rb    = tid >> 5;

    const float* __restrict__ xp = x + (size_t)plane * (W * W);

    Pf pf[3];
    pf_tile(xp, (half * TPB) * TILE_IN, g, rb, pf);

    #pragma unroll
    for (int t = 0; t < TPB; ++t) {
        const int tile_abs = half * TPB + t;
        const int buf = t & 1;
        // consume prefetched regs (compiler inserts vmcnt wait), write LDS
        hwrite(pf, g, rb, slo[buf], shi[buf]);
        __syncthreads();                               // one barrier per tile
        if (t + 1 < TPB)
            pf_tile(xp, (tile_abs + 1) * TILE_IN, g, rb, pf);   // hide under phase2
        phase2(slo[buf], shi[buf], tid, tile_abs, plane, out_ll, out_r);
    }
}

extern "C" void kernel_launch(void* const* d_in, const int* in_sizes, int n_in,
                              void* d_out, int out_size, void* d_ws, size_t ws_size,
                              hipStream_t stream) {
    const float* x = (const float*)d_in[0];
    float* out = (float*)d_out;
    float* out_ll = out;                 // 32*64*64*64 = 8388608 floats
    float* out_r  = out + 8388608;       // 32*384*64*64 = 50331648 floats

    dim3 grid(4096);                     // 2048 planes * 2 halves
    dim3 block(256);
    hipLaunchKernelGGL(scat_j1_kernel, grid, block, 0, stream, x, out_ll, out_r);
}

// Round 7
// 80.477 us; speedup vs baseline: 1.1980x; 1.1061x over previous
//
#include <hip/hip_runtime.h>
#include <math.h>

#define W 128
#define LROWS 22                   // 16 rows + 6 halo
#define TILE_IN 16
#define TILE_OUT 8
#define NTILES 8

typedef float f2_t __attribute__((ext_vector_type(2)));

__device__ __forceinline__ int refl128(int i) {
    i = (i < 0) ? (-1 - i) : i;    // symmetric (half-sample) reflect
    return (i > 127) ? (255 - i) : i;
}

__device__ __forceinline__ float magf(float re, float im) {
    return sqrtf(fmaf(re, re, fmaf(im, im, 1.0e-4f))) - 0.01f;
}

__device__ __forceinline__ void st2(float* p, float a, float b) {
    f2_t v; v.x = a; v.y = b;
    __builtin_nontemporal_store(v, (f2_t*)p);
}

__device__ __forceinline__ float4 add4(float4 a, float4 b) {
    return make_float4(a.x + b.x, a.y + b.y, a.z + b.z, a.w + b.w);
}
__device__ __forceinline__ float4 mul4(float k, float4 a) {
    return make_float4(k * a.x, k * a.y, k * a.z, k * a.w);
}
__device__ __forceinline__ float4 fma4(float k, float4 a, float4 acc) {
    return make_float4(fmaf(k, a.x, acc.x), fmaf(k, a.y, acc.y),
                       fmaf(k, a.z, acc.z), fmaf(k, a.w, acc.w));
}

__global__ __launch_bounds__(256) void scat_j1_kernel(
    const float* __restrict__ x,
    float* __restrict__ out_ll,
    float* __restrict__ out_r)
{
    __shared__ float slo[LROWS][W];
    __shared__ float shi[LROWS][W];

    // XCD-chunked swizzle: grid 16384 = 8 * 2048, bijective.
    const int raw   = blockIdx.x;
    const int L_id  = (raw & 7) * 2048 + (raw >> 3);
    const int plane = L_id >> 3;       // n*64 + c   (0..2047)
    const int tile  = L_id & 7;        // 0..7
    const int r0    = tile * TILE_IN;
    const int tid   = threadIdx.x;

    const float* __restrict__ xp = x + (size_t)plane * (W * W);

    // ---- Phase 1: horizontal 5/7-tap filters (vectorized), write lo/hi to LDS ----
    {
        const int g  = tid & 31;       // 4-col group 0..31
        const int rb = tid >> 5;       // 0..7 row within pass
        #pragma unroll
        for (int it = 0; it < 3; ++it) {
            const int lr = it * 8 + rb;           // 0..23
            if (lr < LROWS) {
                const int q = refl128(r0 - 3 + lr);
                const float4* __restrict__ rv = (const float4*)(xp + (size_t)q * W);
                const float4 B = rv[g];
                float4 A = rv[g > 0 ? g - 1 : 0];
                float4 C = rv[g < 31 ? g + 1 : 31];
                const float4 revB = make_float4(B.w, B.z, B.y, B.x);
                if (g == 0)  A = revB;            // cols -4..-1 reflected
                if (g == 31) C = revB;            // cols 128..131 reflected
                const float wv[10] = {A.y, A.z, A.w, B.x, B.y, B.z, B.w, C.x, C.y, C.z};
                float4 lo4, hi4;
                float* lop = &lo4.x;
                float* hp  = &hi4.x;
                #pragma unroll
                for (int j = 0; j < 4; ++j) {
                    const float sA = wv[j]     + wv[j + 6];
                    const float sB = wv[j + 1] + wv[j + 5];
                    const float sC = wv[j + 2] + wv[j + 4];
                    const float ct = wv[j + 3];
                    lop[j] = fmaf(-0.05f, sB, fmaf(0.25f, sC, 0.5f * ct));
                    hp[j]  = fmaf(-0.0107143f, sA,
                             fmaf( 0.0535714f, sB,
                             fmaf( 0.2607143f, sC, -0.6071429f * ct)));
                }
                ((float4*)&slo[lr][0])[g] = lo4;
                ((float4*)&shi[lr][0])[g] = hi4;
            }
        }
    }
    __syncthreads();

    // ---- Phase 2: float4-wide vertical filters + q2c + magnitudes + ll pool ----
    // thread = (col-pair cp 0..31, output half-row Ib 0..7)
    const int cp = tid & 31;
    const int Ib = tid >> 5;
    const int R0 = 2 * Ib;             // LDS window start (7-tap top row)
    const int n  = plane >> 6;
    const int ch = plane & 63;

    // band taps folded with 1/sqrt(2); ll taps folded with 0.25 (no 1/sqrt2, no bias)
    const float S   = 0.70710678118654752f;
    const float a7  = -0.0107143f * S, b7c = 0.0535714f * S,
                c7  =  0.2607143f * S, d7c = -0.6071429f * S;
    const float a5s = -0.05f * S, b5s = 0.25f * S, c5s = 0.5f * S;
    const float p5a = -0.0125f, p5b = 0.0625f, p5c = 0.125f;

    float m15_0, m15_1, m165_0, m165_1, ll0, ll1;
    {   // L band: lh (15/165) + ll
        float4 v[8];
        #pragma unroll
        for (int t = 0; t < 8; ++t) v[t] = ((const float4*)&slo[R0 + t][0])[cp];
        const float4 s06 = add4(v[0], v[6]), s15 = add4(v[1], v[5]),
                     s24 = add4(v[2], v[4]), s17 = add4(v[1], v[7]),
                     s26 = add4(v[2], v[6]), s35 = add4(v[3], v[5]);
        const float4 t7 = fma4(a7, s06, fma4(b7c, s15, fma4(c7, s24, mul4(d7c, v[3]))));
        const float4 bo = fma4(a7, s17, fma4(b7c, s26, fma4(c7, s35, mul4(d7c, v[4]))));
        const float4 lt = fma4(p5a, s15, fma4(p5b, s24, mul4(p5c, v[3])));
        const float4 lb = fma4(p5a, s26, fma4(p5b, s35, mul4(p5c, v[4])));
        m15_0  = magf(t7.x - bo.y, t7.y + bo.x);
        m15_1  = magf(t7.z - bo.w, t7.w + bo.z);
        m165_0 = magf(t7.x + bo.y, t7.y - bo.x);
        m165_1 = magf(t7.z + bo.w, t7.w - bo.z);
        ll0 = (lt.x + lt.y) + (lb.x + lb.y);
        ll1 = (lt.z + lt.w) + (lb.z + lb.w);
    }
    float m45_0, m45_1, m135_0, m135_1, m75_0, m75_1, m105_0, m105_1;
    {   // H band: hh (45/135) + hl (75/105)
        float4 v[8];
        #pragma unroll
        for (int t = 0; t < 8; ++t) v[t] = ((const float4*)&shi[R0 + t][0])[cp];
        const float4 s06 = add4(v[0], v[6]), s15 = add4(v[1], v[5]),
                     s24 = add4(v[2], v[4]), s17 = add4(v[1], v[7]),
                     s26 = add4(v[2], v[6]), s35 = add4(v[3], v[5]);
        const float4 t7 = fma4(a7, s06, fma4(b7c, s15, fma4(c7, s24, mul4(d7c, v[3]))));
        const float4 bo = fma4(a7, s17, fma4(b7c, s26, fma4(c7, s35, mul4(d7c, v[4]))));
        const float4 ht = fma4(a5s, s15, fma4(b5s, s24, mul4(c5s, v[3])));
        const float4 hb = fma4(a5s, s26, fma4(b5s, s35, mul4(c5s, v[4])));
        m45_0  = magf(t7.x - bo.y, t7.y + bo.x);
        m45_1  = magf(t7.z - bo.w, t7.w + bo.z);
        m135_0 = magf(t7.x + bo.y, t7.y - bo.x);
        m135_1 = magf(t7.z + bo.w, t7.w - bo.z);
        m75_0  = magf(ht.x - hb.y, ht.y + hb.x);
        m75_1  = magf(ht.z - hb.w, ht.w + hb.z);
        m105_0 = magf(ht.x + hb.y, ht.y - hb.x);
        m105_1 = magf(ht.z + hb.w, ht.w - hb.z);
    }

    const int I  = tile * TILE_OUT + Ib;
    const int J0 = 2 * cp;

    st2(out_ll + (size_t)plane * 4096 + (size_t)I * 64 + J0, ll0, ll1);

    float* rp = out_r + ((size_t)(n * 384 + ch)) * 4096 + (size_t)I * 64 + J0;
    st2(rp + 0u * 262144u, m15_0,  m15_1);
    st2(rp + 1u * 262144u, m45_0,  m45_1);
    st2(rp + 2u * 262144u, m75_0,  m75_1);
    st2(rp + 3u * 262144u, m105_0, m105_1);
    st2(rp + 4u * 262144u, m135_0, m135_1);
    st2(rp + 5u * 262144u, m165_0, m165_1);
}

extern "C" void kernel_launch(void* const* d_in, const int* in_sizes, int n_in,
                              void* d_out, int out_size, void* d_ws, size_t ws_size,
                              hipStream_t stream) {
    const float* x = (const float*)d_in[0];
    float* out = (float*)d_out;
    float* out_ll = out;                 // 32*64*64*64 = 8388608 floats
    float* out_r  = out + 8388608;       // 32*384*64*64 = 50331648 floats

    dim3 grid(2048 * NTILES);            // (n*c) planes * 8 row-tiles
    dim3 block(256);
    hipLaunchKernelGGL(scat_j1_kernel, grid, block, 0, stream, x, out_ll, out_r);
}

// Round 8
// 75.941 us; speedup vs baseline: 1.2696x; 1.0597x over previous
//
#include <hip/hip_runtime.h>
#include <math.h>

#define W 128
#define LROWS 22                   // 16 rows + 6 halo
#define TILE_IN 16
#define TILE_OUT 8
#define NTILES 8

typedef float f4 __attribute__((ext_vector_type(4)));
typedef float f2 __attribute__((ext_vector_type(2)));

__device__ __forceinline__ int refl128(int i) {
    i = (i < 0) ? (-1 - i) : i;    // symmetric (half-sample) reflect
    return (i > 127) ? (255 - i) : i;
}

// packed magnitude for two output columns at once
__device__ __forceinline__ f2 mag2(f2 re, f2 im) {
    f2 t = re * re + im * im + 1.0e-4f;
    f2 s = __builtin_elementwise_sqrt(t);
    return s - 0.01f;
}

__device__ __forceinline__ void st2v(float* p, f2 v) {
    __builtin_nontemporal_store(v, (f2*)p);
}

__global__ __launch_bounds__(256) void scat_j1_kernel(
    const float* __restrict__ x,
    float* __restrict__ out_ll,
    float* __restrict__ out_r)
{
    __shared__ float slo[LROWS][W];
    __shared__ float shi[LROWS][W];

    // XCD-chunked swizzle: grid 16384 = 8 * 2048, bijective.
    const int raw   = blockIdx.x;
    const int L_id  = (raw & 7) * 2048 + (raw >> 3);
    const int plane = L_id >> 3;       // n*64 + c   (0..2047)
    const int tile  = L_id & 7;        // 0..7
    const int r0    = tile * TILE_IN;
    const int tid   = threadIdx.x;

    const float* __restrict__ xp = x + (size_t)plane * (W * W);

    // ---- Phase 1: horizontal 5/7-tap filters (vector/packed), write lo/hi to LDS ----
    {
        const int g  = tid & 31;       // 4-col group 0..31
        const int rb = tid >> 5;       // 0..7 row within pass
        #pragma unroll
        for (int it = 0; it < 3; ++it) {
            const int lr = it * 8 + rb;           // 0..23
            if (lr < LROWS) {
                const int q = refl128(r0 - 3 + lr);
                const f4* __restrict__ rv = (const f4*)(xp + (size_t)q * W);
                const f4 B = rv[g];
                f4 A = rv[g > 0 ? g - 1 : 0];
                f4 C = rv[g < 31 ? g + 1 : 31];
                const f4 revB = __builtin_shufflevector(B, B, 3, 2, 1, 0);
                if (g == 0)  A = revB;            // cols -4..-1 reflected
                if (g == 31) C = revB;            // cols 128..131 reflected
                // shifted windows over cols 4g-3 .. 4g+6 (register renames)
                const f4 m0 = __builtin_shufflevector(A, B, 1, 2, 3, 4);
                const f4 m1 = __builtin_shufflevector(A, B, 2, 3, 4, 5);
                const f4 m2 = __builtin_shufflevector(A, B, 3, 4, 5, 6);
                const f4 m3 = B;
                const f4 m4 = __builtin_shufflevector(B, C, 1, 2, 3, 4);
                const f4 m5 = __builtin_shufflevector(B, C, 2, 3, 4, 5);
                const f4 m6 = __builtin_shufflevector(B, C, 3, 4, 5, 6);
                const f4 s06 = m0 + m6;
                const f4 s15 = m1 + m5;
                const f4 s24 = m2 + m4;
                const f4 lo4 = -0.05f * s15 + 0.25f * s24 + 0.5f * m3;
                const f4 hi4 = -0.0107143f * s06 + 0.0535714f * s15
                             +  0.2607143f * s24 + -0.6071429f * m3;
                ((f4*)&slo[lr][0])[g] = lo4;
                ((f4*)&shi[lr][0])[g] = hi4;
            }
        }
    }
    __syncthreads();

    // ---- Phase 2: packed vertical filters + q2c + magnitudes + ll pool ----
    // thread = (col-pair cp 0..31 -> output cols 2cp,2cp+1; half-row Ib 0..7)
    const int cp = tid & 31;
    const int Ib = tid >> 5;
    const int R0 = 2 * Ib;             // LDS window start (7-tap top row)
    const int n  = plane >> 6;
    const int ch = plane & 63;

    // band taps folded with 1/sqrt(2); ll taps folded with 0.25
    const float S   = 0.70710678118654752f;
    const float a7  = -0.0107143f * S, b7 = 0.0535714f * S,
                c7  =  0.2607143f * S, d7 = -0.6071429f * S;
    const float a5s = -0.05f * S, b5s = 0.25f * S, c5s = 0.5f * S;
    const float p5a = -0.0125f, p5b = 0.0625f, p5c = 0.125f;

    f2 m15, m165, m45, m135, m75, m105, llv;
    {   // L band: lh (15/165) + ll
        f4 v0 = ((const f4*)&slo[R0 + 0][0])[cp];
        f4 v1 = ((const f4*)&slo[R0 + 1][0])[cp];
        f4 v2 = ((const f4*)&slo[R0 + 2][0])[cp];
        f4 v3 = ((const f4*)&slo[R0 + 3][0])[cp];
        f4 v4 = ((const f4*)&slo[R0 + 4][0])[cp];
        f4 v5 = ((const f4*)&slo[R0 + 5][0])[cp];
        f4 v6 = ((const f4*)&slo[R0 + 6][0])[cp];
        f4 v7 = ((const f4*)&slo[R0 + 7][0])[cp];
        const f4 s06 = v0 + v6, s15 = v1 + v5, s24 = v2 + v4;
        const f4 s17 = v1 + v7, s26 = v2 + v6, s35 = v3 + v5;
        const f4 t7 = a7 * s06 + b7 * s15 + c7 * s24 + d7 * v3;
        const f4 bo = a7 * s17 + b7 * s26 + c7 * s35 + d7 * v4;
        const f4 lt = p5a * s15 + p5b * s24 + p5c * v3;
        const f4 lb = p5a * s26 + p5b * s35 + p5c * v4;
        const f2 e  = __builtin_shufflevector(t7, t7, 0, 2);
        const f2 eo = __builtin_shufflevector(t7, t7, 1, 3);
        const f2 o  = __builtin_shufflevector(bo, bo, 1, 3);
        const f2 oo = __builtin_shufflevector(bo, bo, 0, 2);
        m15  = mag2(e - o, eo + oo);
        m165 = mag2(e + o, eo - oo);
        const f4 sl = lt + lb;
        llv.x = sl.x + sl.y;
        llv.y = sl.z + sl.w;
    }
    {   // H band: hh (45/135) + hl (75/105)
        f4 v0 = ((const f4*)&shi[R0 + 0][0])[cp];
        f4 v1 = ((const f4*)&shi[R0 + 1][0])[cp];
        f4 v2 = ((const f4*)&shi[R0 + 2][0])[cp];
        f4 v3 = ((const f4*)&shi[R0 + 3][0])[cp];
        f4 v4 = ((const f4*)&shi[R0 + 4][0])[cp];
        f4 v5 = ((const f4*)&shi[R0 + 5][0])[cp];
        f4 v6 = ((const f4*)&shi[R0 + 6][0])[cp];
        f4 v7 = ((const f4*)&shi[R0 + 7][0])[cp];
        const f4 s06 = v0 + v6, s15 = v1 + v5, s24 = v2 + v4;
        const f4 s17 = v1 + v7, s26 = v2 + v6, s35 = v3 + v5;
        const f4 t7 = a7 * s06 + b7 * s15 + c7 * s24 + d7 * v3;
        const f4 bo = a7 * s17 + b7 * s26 + c7 * s35 + d7 * v4;
        const f4 ht = a5s * s15 + b5s * s24 + c5s * v3;
        const f4 hb = a5s * s26 + b5s * s35 + c5s * v4;
        {
            const f2 e  = __builtin_shufflevector(t7, t7, 0, 2);
            const f2 eo = __builtin_shufflevector(t7, t7, 1, 3);
            const f2 o  = __builtin_shufflevector(bo, bo, 1, 3);
            const f2 oo = __builtin_shufflevector(bo, bo, 0, 2);
            m45  = mag2(e - o, eo + oo);
            m135 = mag2(e + o, eo - oo);
        }
        {
            const f2 e  = __builtin_shufflevector(ht, ht, 0, 2);
            const f2 eo = __builtin_shufflevector(ht, ht, 1, 3);
            const f2 o  = __builtin_shufflevector(hb, hb, 1, 3);
            const f2 oo = __builtin_shufflevector(hb, hb, 0, 2);
            m75  = mag2(e - o, eo + oo);
            m105 = mag2(e + o, eo - oo);
        }
    }

    const int I  = tile * TILE_OUT + Ib;
    const int J0 = 2 * cp;

    st2v(out_ll + (size_t)plane * 4096 + (size_t)I * 64 + J0, llv);

    float* rp = out_r + ((size_t)(n * 384 + ch)) * 4096 + (size_t)I * 64 + J0;
    st2v(rp + 0u * 262144u, m15);
    st2v(rp + 1u * 262144u, m45);
    st2v(rp + 2u * 262144u, m75);
    st2v(rp + 3u * 262144u, m105);
    st2v(rp + 4u * 262144u, m135);
    st2v(rp + 5u * 262144u, m165);
}

extern "C" void kernel_launch(void* const* d_in, const int* in_sizes, int n_in,
                              void* d_out, int out_size, void* d_ws, size_t ws_size,
                              hipStream_t stream) {
    const float* x = (const float*)d_in[0];
    float* out = (float*)d_out;
    float* out_ll = out;                 // 32*64*64*64 = 8388608 floats
    float* out_r  = out + 8388608;       // 32*384*64*64 = 50331648 floats

    dim3 grid(2048 * NTILES);            // (n*c) planes * 8 row-tiles
    dim3 block(256);
    hipLaunchKernelGGL(scat_j1_kernel, grid, block, 0, stream, x, out_ll, out_r);
}